// Round 1
// baseline (1572.649 us; speedup 1.0000x reference)
//
#include <hip/hip_runtime.h>
#include <math.h>

#define HW 4096
#define CCH 512
#define C4 128
#define NK 64
#define NBATCH 16

// ---- ws layout (float offsets) ----
// region0 [0, 33554432): h1 [0,8388608), h2 [8388608,16777216); later y [0,33554432)
#define OFF_H1   0
#define OFF_H2   8388608
#define OFF_Y    0
#define OFF_A    33554432ULL   // 16*64*4096 = 4194304
#define OFF_PE   37748736ULL   // 16*4*64*512 = 2097152
#define OFF_ASUM 39845888ULL   // 1024
#define OFF_GAM  39846912ULL   // 8192
#define OFF_MISC 39855104ULL   // 4096
#define OFF_W1F  39859200ULL   // 65536
#define OFF_W2F  39924736ULL   // 147456
#define OFF_W3F  40072192ULL   // 65536
#define OFF_WRF  40137728ULL   // 262144
#define OFF_WLF  40399872ULL   // 262144
// end = 40662016 floats = 155.1 MiB

// misc sub-offsets
#define MS_S1 0
#define MS_T1 128
#define MS_S2 256
#define MS_T2 384
#define MS_S3 512
#define MS_T3 1024
#define MS_SR 1536
#define MS_TR 2048
#define MS_SL 2560
#define MS_TL 3072
#define MS_SE 3584
#define MS_TE 3648
#define MS_CSQ 3712

// ---------------- prep: fold BN params, c_sq ----------------
__global__ void prep_kernel(
    const float* __restrict__ g1, const float* __restrict__ b1, const float* __restrict__ m1, const float* __restrict__ v1,
    const float* __restrict__ g2, const float* __restrict__ b2, const float* __restrict__ m2, const float* __restrict__ v2,
    const float* __restrict__ g3, const float* __restrict__ b3, const float* __restrict__ m3, const float* __restrict__ v3,
    const float* __restrict__ gr, const float* __restrict__ br, const float* __restrict__ mr, const float* __restrict__ vr,
    const float* __restrict__ gl, const float* __restrict__ bl, const float* __restrict__ ml, const float* __restrict__ vl,
    const float* __restrict__ ge, const float* __restrict__ be, const float* __restrict__ me, const float* __restrict__ ve,
    const float* __restrict__ cw, float* __restrict__ misc)
{
  const int t = threadIdx.x;
  if (t < 128) {
    float s = g1[t] * rsqrtf(v1[t] + 1e-6f);
    misc[MS_S1 + t] = s; misc[MS_T1 + t] = b1[t] - m1[t] * s;
    s = g2[t] * rsqrtf(v2[t] + 1e-6f);
    misc[MS_S2 + t] = s; misc[MS_T2 + t] = b2[t] - m2[t] * s;
  }
  for (int c = t; c < 512; c += 256) {
    float s = g3[c] * rsqrtf(v3[c] + 1e-6f);
    misc[MS_S3 + c] = s; misc[MS_T3 + c] = b3[c] - m3[c] * s;
    s = gr[c] * rsqrtf(vr[c] + 1e-6f);
    misc[MS_SR + c] = s; misc[MS_TR + c] = br[c] - mr[c] * s;
    s = gl[c] * rsqrtf(vl[c] + 1e-5f);
    misc[MS_SL + c] = s; misc[MS_TL + c] = bl[c] - ml[c] * s;
  }
  if (t < 64) {
    float s = ge[t] * rsqrtf(ve[t] + 1e-5f);
    misc[MS_SE + t] = s; misc[MS_TE + t] = be[t] - me[t] * s;
    float acc = 0.f;
    for (int c = 0; c < 512; ++c) { float v = cw[t * 512 + c]; acc += v * v; }
    misc[MS_CSQ + t] = acc;
  }
}

// ---------------- fold weights: out = w * s[i/kper] ----------------
__global__ void fold_kernel(const float* __restrict__ w, const float* __restrict__ s,
                            float* __restrict__ out, int total, int kper)
{
  int i = blockIdx.x * 256 + threadIdx.x;
  if (i < total) out[i] = w[i] * s[i / kper];
}

// ---------------- 1x1 conv GEMM (optional dual for conv3+residual) ----------------
// Y[b][m0+m][n0+n] = epilogue( sum_k W[m][k] * X[b][k][n] )
// DUAL: acc = relu(acc + bias1) after phase0, then accumulate phase2, store acc + bias2.
template<bool DUAL, bool RELU_OUT>
__global__ __launch_bounds__(256) void gemm1x1_kernel(
    const float* __restrict__ X1, const float* __restrict__ W1, const float* __restrict__ bias1,
    const float* __restrict__ X2, const float* __restrict__ W2, const float* __restrict__ bias2,
    float* __restrict__ Y, int Cin1, int Cin2, int Cout)
{
  __shared__ __align__(16) float As[8][128];
  __shared__ __align__(16) float Bs[8][128];
  const int tid = threadIdx.x;
  const int b  = blockIdx.z;
  const int n0 = blockIdx.x * 128;
  const int m0 = blockIdx.y * 128;
  const int tr = tid >> 4, tc = tid & 15;
  const int la_m = tid >> 1, la_k = (tid & 1) * 4;
  const int lb_k = tid >> 5, lb_n = (tid & 31) * 4;

  float acc[8][8];
#pragma unroll
  for (int i = 0; i < 8; ++i)
#pragma unroll
    for (int j = 0; j < 8; ++j) acc[i][j] = 0.f;

  const int nphase = DUAL ? 2 : 1;
  for (int phase = 0; phase < nphase; ++phase) {
    const float* __restrict__ X = (phase == 0) ? X1 : X2;
    const float* __restrict__ W = (phase == 0) ? W1 : W2;
    const int K = (phase == 0) ? Cin1 : Cin2;
    const float* __restrict__ Xb = X + (size_t)b * K * HW;

    for (int kt = 0; kt < K; kt += 8) {
      const float4 av = *(const float4*)(W + (size_t)(m0 + la_m) * K + kt + la_k);
      const float4 bv = *(const float4*)(Xb + (size_t)(kt + lb_k) * HW + n0 + lb_n);
      __syncthreads();
      As[la_k + 0][la_m] = av.x;
      As[la_k + 1][la_m] = av.y;
      As[la_k + 2][la_m] = av.z;
      As[la_k + 3][la_m] = av.w;
      *(float4*)&Bs[lb_k][lb_n] = bv;
      __syncthreads();
#pragma unroll
      for (int kk = 0; kk < 8; ++kk) {
        const float4 a0 = *(const float4*)&As[kk][tr * 4];
        const float4 a1 = *(const float4*)&As[kk][64 + tr * 4];
        const float4 b0 = *(const float4*)&Bs[kk][tc * 4];
        const float4 b1 = *(const float4*)&Bs[kk][64 + tc * 4];
        const float am[8] = {a0.x, a0.y, a0.z, a0.w, a1.x, a1.y, a1.z, a1.w};
        const float bn_[8] = {b0.x, b0.y, b0.z, b0.w, b1.x, b1.y, b1.z, b1.w};
#pragma unroll
        for (int i = 0; i < 8; ++i)
#pragma unroll
          for (int j = 0; j < 8; ++j) acc[i][j] += am[i] * bn_[j];
      }
    }
    if (DUAL && phase == 0) {
#pragma unroll
      for (int i = 0; i < 8; ++i) {
        const int m = (i < 4) ? (tr * 4 + i) : (64 + tr * 4 + i - 4);
        const float bb = bias1[m0 + m];
#pragma unroll
        for (int j = 0; j < 8; ++j) acc[i][j] = fmaxf(acc[i][j] + bb, 0.f);
      }
    }
  }

  float* __restrict__ Yb = Y + (size_t)b * Cout * HW;
  const float* __restrict__ bias_f = DUAL ? bias2 : bias1;
#pragma unroll
  for (int i = 0; i < 8; ++i) {
    const int m = (i < 4) ? (tr * 4 + i) : (64 + tr * 4 + i - 4);
    const float bb = bias_f[m0 + m];
    float4 v0, v1;
    v0.x = acc[i][0] + bb; v0.y = acc[i][1] + bb; v0.z = acc[i][2] + bb; v0.w = acc[i][3] + bb;
    v1.x = acc[i][4] + bb; v1.y = acc[i][5] + bb; v1.z = acc[i][6] + bb; v1.w = acc[i][7] + bb;
    if (RELU_OUT) {
      v0.x = fmaxf(v0.x, 0.f); v0.y = fmaxf(v0.y, 0.f); v0.z = fmaxf(v0.z, 0.f); v0.w = fmaxf(v0.w, 0.f);
      v1.x = fmaxf(v1.x, 0.f); v1.y = fmaxf(v1.y, 0.f); v1.z = fmaxf(v1.z, 0.f); v1.w = fmaxf(v1.w, 0.f);
    }
    *(float4*)(Yb + (size_t)(m0 + m) * HW + n0 + tc * 4) = v0;
    *(float4*)(Yb + (size_t)(m0 + m) * HW + n0 + 64 + tc * 4) = v1;
  }
}

// ---------------- conv 3x3 (pad=1) as implicit GEMM, Cin=128, Cout=128 ----------------
__global__ __launch_bounds__(256) void conv3x3_kernel(
    const float* __restrict__ X, const float* __restrict__ Wf, const float* __restrict__ bias,
    float* __restrict__ Y)
{
  __shared__ __align__(16) float As[8][128];
  __shared__ __align__(16) float Bs[8][128];
  const int tid = threadIdx.x;
  const int b  = blockIdx.z;
  const int n0 = blockIdx.x * 128;    // two image rows: h0, h0+1
  const int h0 = n0 >> 6;
  const int tr = tid >> 4, tc = tid & 15;
  const int la_m = tid >> 1, la_k = (tid & 1) * 4;
  const int lb_k = tid >> 5, lb_nl = (tid & 31) * 4;
  const float* __restrict__ Xb = X + (size_t)b * C4 * HW;

  float acc[8][8];
#pragma unroll
  for (int i = 0; i < 8; ++i)
#pragma unroll
    for (int j = 0; j < 8; ++j) acc[i][j] = 0.f;

  for (int kt = 0; kt < 1152; kt += 8) {
    const float4 av = *(const float4*)(Wf + (size_t)la_m * 1152 + kt + la_k);
    // im2col B row: k = ci*9 + ky*3 + kx
    const int kg = kt + lb_k;
    const int ci = kg / 9;
    const int r  = kg - ci * 9;
    const int ky = r / 3;
    const int kx = r - ky * 3;
    const int hh = h0 + (lb_nl >> 6) + ky - 1;
    float bvx = 0.f, bvy = 0.f, bvz = 0.f, bvw = 0.f;
    if ((unsigned)hh < 64u) {
      const float* rowp = Xb + (size_t)ci * HW + hh * 64;
      const int wb = (lb_nl & 63) + kx - 1;
      if ((unsigned)(wb + 0) < 64u) bvx = rowp[wb + 0];
      if ((unsigned)(wb + 1) < 64u) bvy = rowp[wb + 1];
      if ((unsigned)(wb + 2) < 64u) bvz = rowp[wb + 2];
      if ((unsigned)(wb + 3) < 64u) bvw = rowp[wb + 3];
    }
    __syncthreads();
    As[la_k + 0][la_m] = av.x;
    As[la_k + 1][la_m] = av.y;
    As[la_k + 2][la_m] = av.z;
    As[la_k + 3][la_m] = av.w;
    Bs[lb_k][lb_nl + 0] = bvx;
    Bs[lb_k][lb_nl + 1] = bvy;
    Bs[lb_k][lb_nl + 2] = bvz;
    Bs[lb_k][lb_nl + 3] = bvw;
    __syncthreads();
#pragma unroll
    for (int kk = 0; kk < 8; ++kk) {
      const float4 a0 = *(const float4*)&As[kk][tr * 4];
      const float4 a1 = *(const float4*)&As[kk][64 + tr * 4];
      const float4 b0 = *(const float4*)&Bs[kk][tc * 4];
      const float4 b1 = *(const float4*)&Bs[kk][64 + tc * 4];
      const float am[8] = {a0.x, a0.y, a0.z, a0.w, a1.x, a1.y, a1.z, a1.w};
      const float bn_[8] = {b0.x, b0.y, b0.z, b0.w, b1.x, b1.y, b1.z, b1.w};
#pragma unroll
      for (int i = 0; i < 8; ++i)
#pragma unroll
        for (int j = 0; j < 8; ++j) acc[i][j] += am[i] * bn_[j];
    }
  }

  float* __restrict__ Yb = Y + (size_t)b * C4 * HW;
#pragma unroll
  for (int i = 0; i < 8; ++i) {
    const int m = (i < 4) ? (tr * 4 + i) : (64 + tr * 4 + i - 4);
    const float bb = bias[m];
    float4 v0, v1;
    v0.x = fmaxf(acc[i][0] + bb, 0.f); v0.y = fmaxf(acc[i][1] + bb, 0.f);
    v0.z = fmaxf(acc[i][2] + bb, 0.f); v0.w = fmaxf(acc[i][3] + bb, 0.f);
    v1.x = fmaxf(acc[i][4] + bb, 0.f); v1.y = fmaxf(acc[i][5] + bb, 0.f);
    v1.z = fmaxf(acc[i][6] + bb, 0.f); v1.w = fmaxf(acc[i][7] + bb, 0.f);
    *(float4*)(Yb + (size_t)m * HW + n0 + tc * 4) = v0;
    *(float4*)(Yb + (size_t)m * HW + n0 + 64 + tc * 4) = v1;
  }
}

// ---------------- assignment: xc GEMM (64 codes x 64 px) + softmax over codes ----------------
// A[b][k][n] = softmax_k( scale[k] * (|y_n|^2 - 2*xc[k][n] + |c_k|^2) )
__global__ __launch_bounds__(256) void assign_kernel(
    const float* __restrict__ Yv, const float* __restrict__ cw, const float* __restrict__ scale,
    const float* __restrict__ misc, float* __restrict__ A)
{
  __shared__ float Cs[16][64];
  __shared__ float Ys[16][64];
  __shared__ float dist[64][65];
  __shared__ float red[4][64];
  __shared__ float xsq[64];
  __shared__ float scl[64];
  __shared__ float csq[64];
  const int tid = threadIdx.x;
  const int b  = blockIdx.y;
  const int n0 = blockIdx.x * 64;
  if (tid < 64) { scl[tid] = scale[tid]; csq[tid] = misc[MS_CSQ + tid]; }
  const float* __restrict__ Yb = Yv + (size_t)b * CCH * HW;
  const int tr = tid >> 4, tc = tid & 15;
  const int lc_k = tid >> 2, lc_c = (tid & 3) * 4;
  const int ly_c0 = tid >> 6, ly_n = tid & 63;

  float acc[4][4];
#pragma unroll
  for (int i = 0; i < 4; ++i)
#pragma unroll
    for (int j = 0; j < 4; ++j) acc[i][j] = 0.f;
  float sq = 0.f;

  for (int c0 = 0; c0 < 512; c0 += 16) {
    const float4 cv = *(const float4*)(cw + (size_t)lc_k * 512 + c0 + lc_c);
    float yv[4];
#pragma unroll
    for (int rr = 0; rr < 4; ++rr)
      yv[rr] = Yb[(size_t)(c0 + ly_c0 + rr * 4) * HW + n0 + ly_n];
    __syncthreads();
    Cs[lc_c + 0][lc_k] = cv.x;
    Cs[lc_c + 1][lc_k] = cv.y;
    Cs[lc_c + 2][lc_k] = cv.z;
    Cs[lc_c + 3][lc_k] = cv.w;
#pragma unroll
    for (int rr = 0; rr < 4; ++rr) {
      Ys[ly_c0 + rr * 4][ly_n] = yv[rr];
      sq += yv[rr] * yv[rr];
    }
    __syncthreads();
#pragma unroll
    for (int ct = 0; ct < 16; ++ct) {
      float rk[4], rn[4];
#pragma unroll
      for (int i = 0; i < 4; ++i) rk[i] = Cs[ct][tr * 4 + i];
#pragma unroll
      for (int j = 0; j < 4; ++j) rn[j] = Ys[ct][tc * 4 + j];
#pragma unroll
      for (int i = 0; i < 4; ++i)
#pragma unroll
        for (int j = 0; j < 4; ++j) acc[i][j] += rk[i] * rn[j];
    }
  }
  // x_sq reduce (4 partials per pixel)
  __syncthreads();
  red[ly_c0][ly_n] = sq;
  __syncthreads();
  if (tid < 64) xsq[tid] = red[0][tid] + red[1][tid] + red[2][tid] + red[3][tid];
  __syncthreads();
  // dist
#pragma unroll
  for (int i = 0; i < 4; ++i)
#pragma unroll
    for (int j = 0; j < 4; ++j) {
      const int k = tr * 4 + i, n = tc * 4 + j;
      dist[k][n] = scl[k] * (xsq[n] - 2.f * acc[i][j] + csq[k]);
    }
  __syncthreads();
  // softmax over k per column; thread = (q = tid>>6 owns 16 k's, n = tid&63)
  const int q = tid >> 6, n = tid & 63;
  float mx = -3.0e38f;
#pragma unroll
  for (int kk = 0; kk < 16; ++kk) mx = fmaxf(mx, dist[q * 16 + kk][n]);
  red[q][n] = mx;
  __syncthreads();
  mx = fmaxf(fmaxf(red[0][n], red[1][n]), fmaxf(red[2][n], red[3][n]));
  __syncthreads();
  float sum = 0.f;
#pragma unroll
  for (int kk = 0; kk < 16; ++kk) {
    const float e = __expf(dist[q * 16 + kk][n] - mx);
    dist[q * 16 + kk][n] = e;
    sum += e;
  }
  red[q][n] = sum;
  __syncthreads();
  sum = red[0][n] + red[1][n] + red[2][n] + red[3][n];
  const float inv = 1.f / sum;
  float* __restrict__ Ab = A + (size_t)b * NK * HW + n0 + n;
#pragma unroll
  for (int kk = 0; kk < 16; ++kk)
    Ab[(size_t)(q * 16 + kk) * HW] = dist[q * 16 + kk][n] * inv;
}

// ---------------- asum[b][k] = sum_n A[b][k][n] ----------------
__global__ void asum_kernel(const float* __restrict__ A, float* __restrict__ asum)
{
  const int bk = blockIdx.x;
  const float* __restrict__ row = A + (size_t)bk * HW;
  const int t = threadIdx.x;
  float p = 0.f;
  for (int i = t * 4; i < HW; i += 1024) {
    const float4 v = *(const float4*)(row + i);
    p += v.x + v.y + v.z + v.w;
  }
  __shared__ float sm[256];
  sm[t] = p;
  __syncthreads();
  for (int s = 128; s > 0; s >>= 1) {
    if (t < s) sm[t] += sm[t + s];
    __syncthreads();
  }
  if (t == 0) asum[bk] = sm[0];
}

// ---------------- enc partial: pe[b][nc][k][c0+c] = sum_{n in chunk} A[b][k][n]*y[b][c0+c][n] ----------------
__global__ __launch_bounds__(256) void enc_kernel(
    const float* __restrict__ A, const float* __restrict__ Yv, float* __restrict__ pe)
{
  __shared__ float At[64][33];
  __shared__ float Yt[64][33];
  const int t = threadIdx.x;
  const int nc = blockIdx.x, ct = blockIdx.y, b = blockIdx.z;
  const int c0 = ct * 64;
  const float* __restrict__ Ab = A + (size_t)b * NK * HW + nc * 1024;
  const float* __restrict__ Yb = Yv + (size_t)b * CCH * HW + (size_t)c0 * HW + nc * 1024;
  const int lr = t >> 2, ln = (t & 3) * 8;
  const int tr = t >> 4, tc = t & 15;

  float acc[4][4];
#pragma unroll
  for (int i = 0; i < 4; ++i)
#pragma unroll
    for (int j = 0; j < 4; ++j) acc[i][j] = 0.f;

  for (int nb = 0; nb < 1024; nb += 32) {
    const float4 a0 = *(const float4*)(Ab + (size_t)lr * HW + nb + ln);
    const float4 a1 = *(const float4*)(Ab + (size_t)lr * HW + nb + ln + 4);
    const float4 y0 = *(const float4*)(Yb + (size_t)lr * HW + nb + ln);
    const float4 y1 = *(const float4*)(Yb + (size_t)lr * HW + nb + ln + 4);
    __syncthreads();
    At[lr][ln + 0] = a0.x; At[lr][ln + 1] = a0.y; At[lr][ln + 2] = a0.z; At[lr][ln + 3] = a0.w;
    At[lr][ln + 4] = a1.x; At[lr][ln + 5] = a1.y; At[lr][ln + 6] = a1.z; At[lr][ln + 7] = a1.w;
    Yt[lr][ln + 0] = y0.x; Yt[lr][ln + 1] = y0.y; Yt[lr][ln + 2] = y0.z; Yt[lr][ln + 3] = y0.w;
    Yt[lr][ln + 4] = y1.x; Yt[lr][ln + 5] = y1.y; Yt[lr][ln + 6] = y1.z; Yt[lr][ln + 7] = y1.w;
    __syncthreads();
#pragma unroll
    for (int nn = 0; nn < 32; ++nn) {
      float rk[4], ry[4];
#pragma unroll
      for (int i = 0; i < 4; ++i) rk[i] = At[tr * 4 + i][nn];
#pragma unroll
      for (int j = 0; j < 4; ++j) ry[j] = Yt[tc * 4 + j][nn];
#pragma unroll
      for (int i = 0; i < 4; ++i)
#pragma unroll
        for (int j = 0; j < 4; ++j) acc[i][j] += rk[i] * ry[j];
    }
  }
#pragma unroll
  for (int i = 0; i < 4; ++i) {
    const int k = tr * 4 + i;
    float4 v;
    v.x = acc[i][0]; v.y = acc[i][1]; v.z = acc[i][2]; v.w = acc[i][3];
    *(float4*)(pe + ((size_t)(b * 4 + nc) * NK + k) * CCH + c0 + tc * 4) = v;
  }
}

// ---------------- en + gate: en[b][c]=mean_k relu(bn1d(enc)); gam=sigmoid(en@wfc^T+bfc) ----------------
__global__ __launch_bounds__(256) void engate_kernel(
    const float* __restrict__ pe, const float* __restrict__ asum, const float* __restrict__ cw,
    const float* __restrict__ misc, const float* __restrict__ wfc, const float* __restrict__ bfc,
    float* __restrict__ gam)
{
  const int b = blockIdx.x;
  const int t = threadIdx.x;
  __shared__ float asum_s[64], se_s[64], te_s[64];
  __shared__ __align__(16) float en_s[512];
  if (t < 64) {
    asum_s[t] = asum[b * 64 + t];
    se_s[t]   = misc[MS_SE + t];
    te_s[t]   = misc[MS_TE + t];
  }
  __syncthreads();
  for (int rep = 0; rep < 2; ++rep) {
    const int c = t + rep * 256;
    float en = 0.f;
    const float* __restrict__ peb = pe + (size_t)b * 4 * NK * CCH + c;
    for (int k = 0; k < 64; ++k) {
      const float ps = peb[(size_t)k * CCH] + peb[(size_t)(64 + k) * CCH] +
                       peb[(size_t)(128 + k) * CCH] + peb[(size_t)(192 + k) * CCH];
      float v = ps - asum_s[k] * cw[k * 512 + c];
      v = v * se_s[k] + te_s[k];
      en += fmaxf(v, 0.f);
    }
    en_s[c] = en * (1.f / 64.f);
  }
  __syncthreads();
  for (int rep = 0; rep < 2; ++rep) {
    const int i = t + rep * 256;
    float a = bfc[i];
    const float4* __restrict__ wrow = (const float4*)(wfc + (size_t)i * 512);
    const float4* __restrict__ ev = (const float4*)en_s;
    for (int j = 0; j < 128; ++j) {
      const float4 w4 = wrow[j];
      const float4 e4 = ev[j];
      a += w4.x * e4.x + w4.y * e4.y + w4.z * e4.z + w4.w * e4.w;
    }
    gam[b * 512 + i] = 1.f / (1.f + __expf(-a));
  }
}

// ---------------- final: out = relu(x1 * (1 + gam[b][c])), in-place on d_out ----------------
__global__ void final_kernel(float* __restrict__ out, const float* __restrict__ gam)
{
  const size_t idx = (size_t)blockIdx.x * 256 + threadIdx.x; // per float4
  const size_t base = idx * 4;
  const int bc = (int)(base >> 12);                          // b*512 + c
  const float g = 1.f + gam[bc];
  float4 v = *(float4*)(out + base);
  v.x = fmaxf(v.x * g, 0.f);
  v.y = fmaxf(v.y * g, 0.f);
  v.z = fmaxf(v.z * g, 0.f);
  v.w = fmaxf(v.w * g, 0.f);
  *(float4*)(out + base) = v;
}

extern "C" void kernel_launch(void* const* d_in, const int* in_sizes, int n_in,
                              void* d_out, int out_size, void* d_ws, size_t ws_size,
                              hipStream_t stream)
{
  const float* x  = (const float*)d_in[0];
  const float* w1 = (const float*)d_in[1];
  const float* g1 = (const float*)d_in[2];
  const float* b1 = (const float*)d_in[3];
  const float* m1 = (const float*)d_in[4];
  const float* v1 = (const float*)d_in[5];
  const float* w2 = (const float*)d_in[6];
  const float* g2 = (const float*)d_in[7];
  const float* b2 = (const float*)d_in[8];
  const float* m2 = (const float*)d_in[9];
  const float* v2 = (const float*)d_in[10];
  const float* w3 = (const float*)d_in[11];
  const float* g3 = (const float*)d_in[12];
  const float* b3 = (const float*)d_in[13];
  const float* m3 = (const float*)d_in[14];
  const float* v3 = (const float*)d_in[15];
  const float* wr = (const float*)d_in[16];
  const float* gr = (const float*)d_in[17];
  const float* br = (const float*)d_in[18];
  const float* mr = (const float*)d_in[19];
  const float* vr = (const float*)d_in[20];
  const float* wl = (const float*)d_in[21];
  const float* gl = (const float*)d_in[22];
  const float* bl = (const float*)d_in[23];
  const float* ml = (const float*)d_in[24];
  const float* vl = (const float*)d_in[25];
  const float* cw = (const float*)d_in[26];
  const float* scale = (const float*)d_in[27];
  const float* ge = (const float*)d_in[28];
  const float* be = (const float*)d_in[29];
  const float* me = (const float*)d_in[30];
  const float* ve = (const float*)d_in[31];
  const float* wfc = (const float*)d_in[32];
  const float* bfc = (const float*)d_in[33];

  float* ws = (float*)d_ws;
  float* h1   = ws + OFF_H1;
  float* h2   = ws + OFF_H2;
  float* y    = ws + OFF_Y;
  float* A    = ws + OFF_A;
  float* pe   = ws + OFF_PE;
  float* asum = ws + OFF_ASUM;
  float* gam  = ws + OFF_GAM;
  float* misc = ws + OFF_MISC;
  float* w1f  = ws + OFF_W1F;
  float* w2f  = ws + OFF_W2F;
  float* w3f  = ws + OFF_W3F;
  float* wrf  = ws + OFF_WRF;
  float* wlf  = ws + OFF_WLF;
  float* x1   = (float*)d_out;   // x1 lives in d_out; final kernel rewrites in place

  // prep: fold BN params + c_sq
  prep_kernel<<<1, 256, 0, stream>>>(g1, b1, m1, v1, g2, b2, m2, v2, g3, b3, m3, v3,
                                     gr, br, mr, vr, gl, bl, ml, vl, ge, be, me, ve,
                                     cw, misc);
  // fold weights
  fold_kernel<<<(65536 + 255) / 256, 256, 0, stream>>>(w1, misc + MS_S1, w1f, 65536, 512);
  fold_kernel<<<(147456 + 255) / 256, 256, 0, stream>>>(w2, misc + MS_S2, w2f, 147456, 1152);
  fold_kernel<<<(65536 + 255) / 256, 256, 0, stream>>>(w3, misc + MS_S3, w3f, 65536, 128);
  fold_kernel<<<(262144 + 255) / 256, 256, 0, stream>>>(wr, misc + MS_SR, wrf, 262144, 512);
  fold_kernel<<<(262144 + 255) / 256, 256, 0, stream>>>(wl, misc + MS_SL, wlf, 262144, 512);

  // K1: h1 = relu(conv1x1(x, w1f) + t1)
  gemm1x1_kernel<false, true><<<dim3(32, 1, 16), 256, 0, stream>>>(
      x, w1f, misc + MS_T1, nullptr, nullptr, nullptr, h1, 512, 0, 128);
  // K2: h2 = relu(conv3x3(h1, w2f) + t2)
  conv3x3_kernel<<<dim3(32, 1, 16), 256, 0, stream>>>(h1, w2f, misc + MS_T2, h2);
  // K3: x1 = relu(conv1x1(h2, w3f) + t3) + conv1x1(x, wrf) + tr
  gemm1x1_kernel<true, false><<<dim3(32, 4, 16), 256, 0, stream>>>(
      h2, w3f, misc + MS_T3, x, wrf, misc + MS_TR, x1, 128, 512, 512);
  // K4: y = relu(conv1x1(x1, wlf) + tl)
  gemm1x1_kernel<false, true><<<dim3(32, 4, 16), 256, 0, stream>>>(
      x1, wlf, misc + MS_TL, nullptr, nullptr, nullptr, y, 512, 0, 512);
  // K5: soft assignment
  assign_kernel<<<dim3(64, 16), 256, 0, stream>>>(y, cw, scale, misc, A);
  // asum
  asum_kernel<<<1024, 256, 0, stream>>>(A, asum);
  // K6: enc partials
  enc_kernel<<<dim3(4, 8, 16), 256, 0, stream>>>(A, y, pe);
  // K7: en + gate
  engate_kernel<<<16, 256, 0, stream>>>(pe, asum, cw, misc, wfc, bfc, gam);
  // K8: out = relu(x1 * (1 + gam)), in place
  final_kernel<<<32768, 256, 0, stream>>>((float*)d_out, gam);
}

// Round 6
// 1297.608 us; speedup vs baseline: 1.2120x; 1.2120x over previous
//
#include <hip/hip_runtime.h>
#include <math.h>

typedef float f32x4 __attribute__((ext_vector_type(4)));
typedef short s16x8 __attribute__((ext_vector_type(8)));

#define HW 4096
#define CCH 512
#define NK 64

// ---- ws layout (float offsets) ---- (same as R1)
#define OFF_H1   0
#define OFF_H2   8388608
#define OFF_Y    0
#define OFF_A    33554432ULL
#define OFF_PE   37748736ULL
#define OFF_ASUM 39845888ULL
#define OFF_GAM  39846912ULL
#define OFF_MISC 39855104ULL
#define OFF_W1F  39859200ULL
#define OFF_W2F  39924736ULL
#define OFF_W3F  40072192ULL
#define OFF_WRF  40137728ULL
#define OFF_WLF  40399872ULL   // reused as bf16 wl (262144 shorts fit in 262144 floats)
// end = 40662016 floats

#define MS_S1 0
#define MS_T1 128
#define MS_S2 256
#define MS_T2 384
#define MS_S3 512
#define MS_T3 1024
#define MS_SR 1536
#define MS_TR 2048
#define MS_SL 2560
#define MS_TL 3072
#define MS_SE 3584
#define MS_TE 3648
#define MS_CSQ 3712

__device__ __forceinline__ unsigned short f2b(float f) {
  unsigned int i = __builtin_bit_cast(unsigned int, f);
  i += 0x7fffu + ((i >> 16) & 1u);
  return (unsigned short)(i >> 16);
}

// ---------------- prep: fold BN params, c_sq ----------------
__global__ void prep_kernel(
    const float* __restrict__ g1, const float* __restrict__ b1, const float* __restrict__ m1, const float* __restrict__ v1,
    const float* __restrict__ g2, const float* __restrict__ b2, const float* __restrict__ m2, const float* __restrict__ v2,
    const float* __restrict__ g3, const float* __restrict__ b3, const float* __restrict__ m3, const float* __restrict__ v3,
    const float* __restrict__ gr, const float* __restrict__ br, const float* __restrict__ mr, const float* __restrict__ vr,
    const float* __restrict__ gl, const float* __restrict__ bl, const float* __restrict__ ml, const float* __restrict__ vl,
    const float* __restrict__ ge, const float* __restrict__ be, const float* __restrict__ me, const float* __restrict__ ve,
    const float* __restrict__ cw, float* __restrict__ misc)
{
  const int t = threadIdx.x;
  if (t < 128) {
    float s = g1[t] * rsqrtf(v1[t] + 1e-6f);
    misc[MS_S1 + t] = s; misc[MS_T1 + t] = b1[t] - m1[t] * s;
    s = g2[t] * rsqrtf(v2[t] + 1e-6f);
    misc[MS_S2 + t] = s; misc[MS_T2 + t] = b2[t] - m2[t] * s;
  }
  for (int c = t; c < 512; c += 256) {
    float s = g3[c] * rsqrtf(v3[c] + 1e-6f);
    misc[MS_S3 + c] = s; misc[MS_T3 + c] = b3[c] - m3[c] * s;
    s = gr[c] * rsqrtf(vr[c] + 1e-6f);
    misc[MS_SR + c] = s; misc[MS_TR + c] = br[c] - mr[c] * s;
    s = gl[c] * rsqrtf(vl[c] + 1e-5f);
    misc[MS_SL + c] = s; misc[MS_TL + c] = bl[c] - ml[c] * s;
  }
  if (t < 64) {
    float s = ge[t] * rsqrtf(ve[t] + 1e-5f);
    misc[MS_SE + t] = s; misc[MS_TE + t] = be[t] - me[t] * s;
    float acc = 0.f;
    for (int c = 0; c < 512; ++c) { float v = cw[t * 512 + c]; acc += v * v; }
    misc[MS_CSQ + t] = acc;
  }
}

// ---------------- fold weights (fp32) ----------------
__global__ void fold_kernel(const float* __restrict__ w, const float* __restrict__ s,
                            float* __restrict__ out, int total, int kper)
{
  int i = blockIdx.x * 256 + threadIdx.x;
  if (i < total) out[i] = w[i] * s[i / kper];
}

// ---------------- fold weights -> bf16 (for MFMA K4) ----------------
__global__ void fold_bf16_kernel(const float* __restrict__ w, const float* __restrict__ s,
                                 unsigned short* __restrict__ out, int total, int kper)
{
  int i = blockIdx.x * 256 + threadIdx.x;
  if (i < total) out[i] = f2b(w[i] * s[i / kper]);
}

// ---------------- 1x1 conv GEMM (optional dual) — R1 verified ----------------
template<bool DUAL, bool RELU_OUT>
__global__ __launch_bounds__(256) void gemm1x1_kernel(
    const float* __restrict__ X1, const float* __restrict__ W1, const float* __restrict__ bias1,
    const float* __restrict__ X2, const float* __restrict__ W2, const float* __restrict__ bias2,
    float* __restrict__ Y, int Cin1, int Cin2, int Cout)
{
  __shared__ __align__(16) float As[8][128];
  __shared__ __align__(16) float Bs[8][128];
  const int tid = threadIdx.x;
  const int b  = blockIdx.z;
  const int n0 = blockIdx.x * 128;
  const int m0 = blockIdx.y * 128;
  const int tr = tid >> 4, tc = tid & 15;
  const int la_m = tid >> 1, la_k = (tid & 1) * 4;
  const int lb_k = tid >> 5, lb_n = (tid & 31) * 4;

  float acc[8][8];
#pragma unroll
  for (int i = 0; i < 8; ++i)
#pragma unroll
    for (int j = 0; j < 8; ++j) acc[i][j] = 0.f;

  const int nphase = DUAL ? 2 : 1;
  for (int phase = 0; phase < nphase; ++phase) {
    const float* __restrict__ X = (phase == 0) ? X1 : X2;
    const float* __restrict__ W = (phase == 0) ? W1 : W2;
    const int K = (phase == 0) ? Cin1 : Cin2;
    const float* __restrict__ Xb = X + (size_t)b * K * HW;

    for (int kt = 0; kt < K; kt += 8) {
      const float4 av = *(const float4*)(W + (size_t)(m0 + la_m) * K + kt + la_k);
      const float4 bv = *(const float4*)(Xb + (size_t)(kt + lb_k) * HW + n0 + lb_n);
      __syncthreads();
      As[la_k + 0][la_m] = av.x;
      As[la_k + 1][la_m] = av.y;
      As[la_k + 2][la_m] = av.z;
      As[la_k + 3][la_m] = av.w;
      *(float4*)&Bs[lb_k][lb_n] = bv;
      __syncthreads();
#pragma unroll
      for (int kk = 0; kk < 8; ++kk) {
        const float4 a0 = *(const float4*)&As[kk][tr * 4];
        const float4 a1 = *(const float4*)&As[kk][64 + tr * 4];
        const float4 b0 = *(const float4*)&Bs[kk][tc * 4];
        const float4 b1 = *(const float4*)&Bs[kk][64 + tc * 4];
        const float am[8] = {a0.x, a0.y, a0.z, a0.w, a1.x, a1.y, a1.z, a1.w};
        const float bn_[8] = {b0.x, b0.y, b0.z, b0.w, b1.x, b1.y, b1.z, b1.w};
#pragma unroll
        for (int i = 0; i < 8; ++i)
#pragma unroll
          for (int j = 0; j < 8; ++j) acc[i][j] += am[i] * bn_[j];
      }
    }
    if (DUAL && phase == 0) {
#pragma unroll
      for (int i = 0; i < 8; ++i) {
        const int m = (i < 4) ? (tr * 4 + i) : (64 + tr * 4 + i - 4);
        const float bb = bias1[m0 + m];
#pragma unroll
        for (int j = 0; j < 8; ++j) acc[i][j] = fmaxf(acc[i][j] + bb, 0.f);
      }
    }
  }

  float* __restrict__ Yb = Y + (size_t)b * Cout * HW;
  const float* __restrict__ bias_f = DUAL ? bias2 : bias1;
#pragma unroll
  for (int i = 0; i < 8; ++i) {
    const int m = (i < 4) ? (tr * 4 + i) : (64 + tr * 4 + i - 4);
    const float bb = bias_f[m0 + m];
    float4 v0, v1;
    v0.x = acc[i][0] + bb; v0.y = acc[i][1] + bb; v0.z = acc[i][2] + bb; v0.w = acc[i][3] + bb;
    v1.x = acc[i][4] + bb; v1.y = acc[i][5] + bb; v1.z = acc[i][6] + bb; v1.w = acc[i][7] + bb;
    if (RELU_OUT) {
      v0.x = fmaxf(v0.x, 0.f); v0.y = fmaxf(v0.y, 0.f); v0.z = fmaxf(v0.z, 0.f); v0.w = fmaxf(v0.w, 0.f);
      v1.x = fmaxf(v1.x, 0.f); v1.y = fmaxf(v1.y, 0.f); v1.z = fmaxf(v1.z, 0.f); v1.w = fmaxf(v1.w, 0.f);
    }
    *(float4*)(Yb + (size_t)(m0 + m) * HW + n0 + tc * 4) = v0;
    *(float4*)(Yb + (size_t)(m0 + m) * HW + n0 + 64 + tc * 4) = v1;
  }
}

// ---------------- conv 3x3 — R1 verified ----------------
__global__ __launch_bounds__(256) void conv3x3_kernel(
    const float* __restrict__ X, const float* __restrict__ Wf, const float* __restrict__ bias,
    float* __restrict__ Y)
{
  __shared__ __align__(16) float As[8][128];
  __shared__ __align__(16) float Bs[8][128];
  const int tid = threadIdx.x;
  const int b  = blockIdx.z;
  const int n0 = blockIdx.x * 128;
  const int h0 = n0 >> 6;
  const int tr = tid >> 4, tc = tid & 15;
  const int la_m = tid >> 1, la_k = (tid & 1) * 4;
  const int lb_k = tid >> 5, lb_nl = (tid & 31) * 4;
  const float* __restrict__ Xb = X + (size_t)b * 128 * HW;

  float acc[8][8];
#pragma unroll
  for (int i = 0; i < 8; ++i)
#pragma unroll
    for (int j = 0; j < 8; ++j) acc[i][j] = 0.f;

  for (int kt = 0; kt < 1152; kt += 8) {
    const float4 av = *(const float4*)(Wf + (size_t)la_m * 1152 + kt + la_k);
    const int kg = kt + lb_k;
    const int ci = kg / 9;
    const int r  = kg - ci * 9;
    const int ky = r / 3;
    const int kx = r - ky * 3;
    const int hh = h0 + (lb_nl >> 6) + ky - 1;
    float bvx = 0.f, bvy = 0.f, bvz = 0.f, bvw = 0.f;
    if ((unsigned)hh < 64u) {
      const float* rowp = Xb + (size_t)ci * HW + hh * 64;
      const int wb = (lb_nl & 63) + kx - 1;
      if ((unsigned)(wb + 0) < 64u) bvx = rowp[wb + 0];
      if ((unsigned)(wb + 1) < 64u) bvy = rowp[wb + 1];
      if ((unsigned)(wb + 2) < 64u) bvz = rowp[wb + 2];
      if ((unsigned)(wb + 3) < 64u) bvw = rowp[wb + 3];
    }
    __syncthreads();
    As[la_k + 0][la_m] = av.x;
    As[la_k + 1][la_m] = av.y;
    As[la_k + 2][la_m] = av.z;
    As[la_k + 3][la_m] = av.w;
    Bs[lb_k][lb_nl + 0] = bvx;
    Bs[lb_k][lb_nl + 1] = bvy;
    Bs[lb_k][lb_nl + 2] = bvz;
    Bs[lb_k][lb_nl + 3] = bvw;
    __syncthreads();
#pragma unroll
    for (int kk = 0; kk < 8; ++kk) {
      const float4 a0 = *(const float4*)&As[kk][tr * 4];
      const float4 a1 = *(const float4*)&As[kk][64 + tr * 4];
      const float4 b0 = *(const float4*)&Bs[kk][tc * 4];
      const float4 b1 = *(const float4*)&Bs[kk][64 + tc * 4];
      const float am[8] = {a0.x, a0.y, a0.z, a0.w, a1.x, a1.y, a1.z, a1.w};
      const float bn_[8] = {b0.x, b0.y, b0.z, b0.w, b1.x, b1.y, b1.z, b1.w};
#pragma unroll
      for (int i = 0; i < 8; ++i)
#pragma unroll
        for (int j = 0; j < 8; ++j) acc[i][j] += am[i] * bn_[j];
    }
  }

  float* __restrict__ Yb = Y + (size_t)b * 128 * HW;
#pragma unroll
  for (int i = 0; i < 8; ++i) {
    const int m = (i < 4) ? (tr * 4 + i) : (64 + tr * 4 + i - 4);
    const float bb = bias[m];
    float4 v0, v1;
    v0.x = fmaxf(acc[i][0] + bb, 0.f); v0.y = fmaxf(acc[i][1] + bb, 0.f);
    v0.z = fmaxf(acc[i][2] + bb, 0.f); v0.w = fmaxf(acc[i][3] + bb, 0.f);
    v1.x = fmaxf(acc[i][4] + bb, 0.f); v1.y = fmaxf(acc[i][5] + bb, 0.f);
    v1.z = fmaxf(acc[i][6] + bb, 0.f); v1.w = fmaxf(acc[i][7] + bb, 0.f);
    *(float4*)(Yb + (size_t)m * HW + n0 + tc * 4) = v0;
    *(float4*)(Yb + (size_t)m * HW + n0 + 64 + tc * 4) = v1;
  }
}

// ============ DIAGNOSTIC: minimal MFMA GEMM for K4 (LVC conv), NO LDS ============
// Tests ONLY: operand row/col = lane&15, shared k-map mu(q,e)=q*8+e cancellation,
// and the HW-verified C/D map (col=lane&15, row=(lane>>4)*4+reg).
// A: bf16 weights [512][512] k-contig, direct 16B loads.
// B: fp32 NCHW x1, per-element gather (coalesced over 16-lane groups) + cvt to bf16.
__global__ __launch_bounds__(256) void mfma_lvc_kernel(
    const unsigned short* __restrict__ Wb, const float* __restrict__ X,
    const float* __restrict__ bias, float* __restrict__ Y)
{
  const int tid = threadIdx.x;
  const int b = blockIdx.z;
  const int n0 = blockIdx.x * 128;
  const int m0 = blockIdx.y * 128;
  const int lane = tid & 63, wv = tid >> 6, wm = wv >> 1, wn = wv & 1;
  const int q = lane >> 4, mm = lane & 15;
  const float* __restrict__ Xb = X + (size_t)b * 512 * HW;

  f32x4 acc[4][4];
#pragma unroll
  for (int i = 0; i < 4; ++i)
#pragma unroll
    for (int j = 0; j < 4; ++j) acc[i][j] = (f32x4){0.f, 0.f, 0.f, 0.f};

  for (int kt = 0; kt < 512; kt += 32) {
    s16x8 afr[4];
#pragma unroll
    for (int i = 0; i < 4; ++i)
      afr[i] = *(const s16x8*)(Wb + (size_t)(m0 + wm * 64 + i * 16 + mm) * 512 + kt + q * 8);
    s16x8 bfr[4];
#pragma unroll
    for (int j = 0; j < 4; ++j) {
      const float* __restrict__ col = Xb + (size_t)(kt + q * 8) * HW + n0 + wn * 64 + j * 16 + mm;
#pragma unroll
      for (int e = 0; e < 8; ++e) bfr[j][e] = (short)f2b(col[(size_t)e * HW]);
    }
#pragma unroll
    for (int i = 0; i < 4; ++i)
#pragma unroll
      for (int j = 0; j < 4; ++j)
        acc[i][j] = __builtin_amdgcn_mfma_f32_16x16x32_bf16(afr[i], bfr[j], acc[i][j], 0, 0, 0);
  }

  float* __restrict__ Yb = Y + (size_t)b * 512 * HW;
#pragma unroll
  for (int i = 0; i < 4; ++i) {
    const int mb = m0 + wm * 64 + i * 16 + q * 4;
#pragma unroll
    for (int j = 0; j < 4; ++j) {
      const int n = n0 + wn * 64 + j * 16 + mm;
#pragma unroll
      for (int r = 0; r < 4; ++r) {
        const float v = fmaxf(acc[i][j][r] + bias[mb + r], 0.f);
        Yb[(size_t)(mb + r) * HW + n] = v;
      }
    }
  }
}

// ---------------- assignment — R1 verified ----------------
__global__ __launch_bounds__(256) void assign_kernel(
    const float* __restrict__ Yv, const float* __restrict__ cw, const float* __restrict__ scale,
    const float* __restrict__ misc, float* __restrict__ A)
{
  __shared__ float Cs[16][64];
  __shared__ float Ys[16][64];
  __shared__ float dist[64][65];
  __shared__ float red[4][64];
  __shared__ float xsq[64];
  __shared__ float scl[64];
  __shared__ float csq[64];
  const int tid = threadIdx.x;
  const int b  = blockIdx.y;
  const int n0 = blockIdx.x * 64;
  if (tid < 64) { scl[tid] = scale[tid]; csq[tid] = misc[MS_CSQ + tid]; }
  const float* __restrict__ Yb = Yv + (size_t)b * CCH * HW;
  const int tr = tid >> 4, tc = tid & 15;
  const int lc_k = tid >> 2, lc_c = (tid & 3) * 4;
  const int ly_c0 = tid >> 6, ly_n = tid & 63;

  float acc[4][4];
#pragma unroll
  for (int i = 0; i < 4; ++i)
#pragma unroll
    for (int j = 0; j < 4; ++j) acc[i][j] = 0.f;
  float sq = 0.f;

  for (int c0 = 0; c0 < 512; c0 += 16) {
    const float4 cv = *(const float4*)(cw + (size_t)lc_k * 512 + c0 + lc_c);
    float yv[4];
#pragma unroll
    for (int rr = 0; rr < 4; ++rr)
      yv[rr] = Yb[(size_t)(c0 + ly_c0 + rr * 4) * HW + n0 + ly_n];
    __syncthreads();
    Cs[lc_c + 0][lc_k] = cv.x;
    Cs[lc_c + 1][lc_k] = cv.y;
    Cs[lc_c + 2][lc_k] = cv.z;
    Cs[lc_c + 3][lc_k] = cv.w;
#pragma unroll
    for (int rr = 0; rr < 4; ++rr) {
      Ys[ly_c0 + rr * 4][ly_n] = yv[rr];
      sq += yv[rr] * yv[rr];
    }
    __syncthreads();
#pragma unroll
    for (int ct = 0; ct < 16; ++ct) {
      float rk[4], rn[4];
#pragma unroll
      for (int i = 0; i < 4; ++i) rk[i] = Cs[ct][tr * 4 + i];
#pragma unroll
      for (int j = 0; j < 4; ++j) rn[j] = Ys[ct][tc * 4 + j];
#pragma unroll
      for (int i = 0; i < 4; ++i)
#pragma unroll
        for (int j = 0; j < 4; ++j) acc[i][j] += rk[i] * rn[j];
    }
  }
  __syncthreads();
  red[ly_c0][ly_n] = sq;
  __syncthreads();
  if (tid < 64) xsq[tid] = red[0][tid] + red[1][tid] + red[2][tid] + red[3][tid];
  __syncthreads();
#pragma unroll
  for (int i = 0; i < 4; ++i)
#pragma unroll
    for (int j = 0; j < 4; ++j) {
      const int k = tr * 4 + i, n = tc * 4 + j;
      dist[k][n] = scl[k] * (xsq[n] - 2.f * acc[i][j] + csq[k]);
    }
  __syncthreads();
  const int qq = tid >> 6, n = tid & 63;
  float mx = -3.0e38f;
#pragma unroll
  for (int kk = 0; kk < 16; ++kk) mx = fmaxf(mx, dist[qq * 16 + kk][n]);
  red[qq][n] = mx;
  __syncthreads();
  mx = fmaxf(fmaxf(red[0][n], red[1][n]), fmaxf(red[2][n], red[3][n]));
  __syncthreads();
  float sum = 0.f;
#pragma unroll
  for (int kk = 0; kk < 16; ++kk) {
    const float e = __expf(dist[qq * 16 + kk][n] - mx);
    dist[qq * 16 + kk][n] = e;
    sum += e;
  }
  red[qq][n] = sum;
  __syncthreads();
  sum = red[0][n] + red[1][n] + red[2][n] + red[3][n];
  const float inv = 1.f / sum;
  float* __restrict__ Ab = A + (size_t)b * NK * HW + n0 + n;
#pragma unroll
  for (int kk = 0; kk < 16; ++kk)
    Ab[(size_t)(qq * 16 + kk) * HW] = dist[qq * 16 + kk][n] * inv;
}

// ---------------- asum — R1 verified ----------------
__global__ void asum_kernel(const float* __restrict__ A, float* __restrict__ asum)
{
  const int bk = blockIdx.x;
  const float* __restrict__ row = A + (size_t)bk * HW;
  const int t = threadIdx.x;
  float p = 0.f;
  for (int i = t * 4; i < HW; i += 1024) {
    const float4 v = *(const float4*)(row + i);
    p += v.x + v.y + v.z + v.w;
  }
  __shared__ float sm[256];
  sm[t] = p;
  __syncthreads();
  for (int s = 128; s > 0; s >>= 1) {
    if (t < s) sm[t] += sm[t + s];
    __syncthreads();
  }
  if (t == 0) asum[bk] = sm[0];
}

// ---------------- enc partial — R1 verified ----------------
__global__ __launch_bounds__(256) void enc_kernel(
    const float* __restrict__ A, const float* __restrict__ Yv, float* __restrict__ pe)
{
  __shared__ float At[64][33];
  __shared__ float Yt[64][33];
  const int t = threadIdx.x;
  const int nc = blockIdx.x, ct = blockIdx.y, b = blockIdx.z;
  const int c0 = ct * 64;
  const float* __restrict__ Ab = A + (size_t)b * NK * HW + nc * 1024;
  const float* __restrict__ Yb = Yv + (size_t)b * CCH * HW + (size_t)c0 * HW + nc * 1024;
  const int lr = t >> 2, ln = (t & 3) * 8;
  const int tr = t >> 4, tc = t & 15;

  float acc[4][4];
#pragma unroll
  for (int i = 0; i < 4; ++i)
#pragma unroll
    for (int j = 0; j < 4; ++j) acc[i][j] = 0.f;

  for (int nb = 0; nb < 1024; nb += 32) {
    const float4 a0 = *(const float4*)(Ab + (size_t)lr * HW + nb + ln);
    const float4 a1 = *(const float4*)(Ab + (size_t)lr * HW + nb + ln + 4);
    const float4 y0 = *(const float4*)(Yb + (size_t)lr * HW + nb + ln);
    const float4 y1 = *(const float4*)(Yb + (size_t)lr * HW + nb + ln + 4);
    __syncthreads();
    At[lr][ln + 0] = a0.x; At[lr][ln + 1] = a0.y; At[lr][ln + 2] = a0.z; At[lr][ln + 3] = a0.w;
    At[lr][ln + 4] = a1.x; At[lr][ln + 5] = a1.y; At[lr][ln + 6] = a1.z; At[lr][ln + 7] = a1.w;
    Yt[lr][ln + 0] = y0.x; Yt[lr][ln + 1] = y0.y; Yt[lr][ln + 2] = y0.z; Yt[lr][ln + 3] = y0.w;
    Yt[lr][ln + 4] = y1.x; Yt[lr][ln + 5] = y1.y; Yt[lr][ln + 6] = y1.z; Yt[lr][ln + 7] = y1.w;
    __syncthreads();
#pragma unroll
    for (int nn = 0; nn < 32; ++nn) {
      float rk[4], ry[4];
#pragma unroll
      for (int i = 0; i < 4; ++i) rk[i] = At[tr * 4 + i][nn];
#pragma unroll
      for (int j = 0; j < 4; ++j) ry[j] = Yt[tc * 4 + j][nn];
#pragma unroll
      for (int i = 0; i < 4; ++i)
#pragma unroll
        for (int j = 0; j < 4; ++j) acc[i][j] += rk[i] * ry[j];
    }
  }
#pragma unroll
  for (int i = 0; i < 4; ++i) {
    const int k = tr * 4 + i;
    float4 v;
    v.x = acc[i][0]; v.y = acc[i][1]; v.z = acc[i][2]; v.w = acc[i][3];
    *(float4*)(pe + ((size_t)(b * 4 + nc) * NK + k) * CCH + c0 + tc * 4) = v;
  }
}

// ---------------- en + gate — R1 verified ----------------
__global__ __launch_bounds__(256) void engate_kernel(
    const float* __restrict__ pe, const float* __restrict__ asum, const float* __restrict__ cw,
    const float* __restrict__ misc, const float* __restrict__ wfc, const float* __restrict__ bfc,
    float* __restrict__ gam)
{
  const int b = blockIdx.x;
  const int t = threadIdx.x;
  __shared__ float asum_s[64], se_s[64], te_s[64];
  __shared__ __align__(16) float en_s[512];
  if (t < 64) {
    asum_s[t] = asum[b * 64 + t];
    se_s[t]   = misc[MS_SE + t];
    te_s[t]   = misc[MS_TE + t];
  }
  __syncthreads();
  for (int rep = 0; rep < 2; ++rep) {
    const int c = t + rep * 256;
    float en = 0.f;
    const float* __restrict__ peb = pe + (size_t)b * 4 * NK * CCH + c;
    for (int k = 0; k < 64; ++k) {
      const float ps = peb[(size_t)k * CCH] + peb[(size_t)(64 + k) * CCH] +
                       peb[(size_t)(128 + k) * CCH] + peb[(size_t)(192 + k) * CCH];
      float v = ps - asum_s[k] * cw[k * 512 + c];
      v = v * se_s[k] + te_s[k];
      en += fmaxf(v, 0.f);
    }
    en_s[c] = en * (1.f / 64.f);
  }
  __syncthreads();
  for (int rep = 0; rep < 2; ++rep) {
    const int i = t + rep * 256;
    float a = bfc[i];
    const float4* __restrict__ wrow = (const float4*)(wfc + (size_t)i * 512);
    const float4* __restrict__ ev = (const float4*)en_s;
    for (int j = 0; j < 128; ++j) {
      const float4 w4 = wrow[j];
      const float4 e4 = ev[j];
      a += w4.x * e4.x + w4.y * e4.y + w4.z * e4.z + w4.w * e4.w;
    }
    gam[b * 512 + i] = 1.f / (1.f + __expf(-a));
  }
}

// ---------------- final — R1 verified ----------------
__global__ void final_kernel(float* __restrict__ out, const float* __restrict__ gam)
{
  const size_t idx = (size_t)blockIdx.x * 256 + threadIdx.x;
  const size_t base = idx * 4;
  const int bc = (int)(base >> 12);
  const float g = 1.f + gam[bc];
  float4 v = *(float4*)(out + base);
  v.x = fmaxf(v.x * g, 0.f);
  v.y = fmaxf(v.y * g, 0.f);
  v.z = fmaxf(v.z * g, 0.f);
  v.w = fmaxf(v.w * g, 0.f);
  *(float4*)(out + base) = v;
}

extern "C" void kernel_launch(void* const* d_in, const int* in_sizes, int n_in,
                              void* d_out, int out_size, void* d_ws, size_t ws_size,
                              hipStream_t stream)
{
  const float* x  = (const float*)d_in[0];
  const float* w1 = (const float*)d_in[1];
  const float* g1 = (const float*)d_in[2];
  const float* b1 = (const float*)d_in[3];
  const float* m1 = (const float*)d_in[4];
  const float* v1 = (const float*)d_in[5];
  const float* w2 = (const float*)d_in[6];
  const float* g2 = (const float*)d_in[7];
  const float* b2 = (const float*)d_in[8];
  const float* m2 = (const float*)d_in[9];
  const float* v2 = (const float*)d_in[10];
  const float* w3 = (const float*)d_in[11];
  const float* g3 = (const float*)d_in[12];
  const float* b3 = (const float*)d_in[13];
  const float* m3 = (const float*)d_in[14];
  const float* v3 = (const float*)d_in[15];
  const float* wr = (const float*)d_in[16];
  const float* gr = (const float*)d_in[17];
  const float* br = (const float*)d_in[18];
  const float* mr = (const float*)d_in[19];
  const float* vr = (const float*)d_in[20];
  const float* wl = (const float*)d_in[21];
  const float* gl = (const float*)d_in[22];
  const float* bl = (const float*)d_in[23];
  const float* ml = (const float*)d_in[24];
  const float* vl = (const float*)d_in[25];
  const float* cw = (const float*)d_in[26];
  const float* scale = (const float*)d_in[27];
  const float* ge = (const float*)d_in[28];
  const float* be = (const float*)d_in[29];
  const float* me = (const float*)d_in[30];
  const float* ve = (const float*)d_in[31];
  const float* wfc = (const float*)d_in[32];
  const float* bfc = (const float*)d_in[33];

  float* ws = (float*)d_ws;
  float* h1   = ws + OFF_H1;
  float* h2   = ws + OFF_H2;
  float* y    = ws + OFF_Y;
  float* A    = ws + OFF_A;
  float* pe   = ws + OFF_PE;
  float* asum = ws + OFF_ASUM;
  float* gam  = ws + OFF_GAM;
  float* misc = ws + OFF_MISC;
  float* w1f  = ws + OFF_W1F;
  float* w2f  = ws + OFF_W2F;
  float* w3f  = ws + OFF_W3F;
  float* wrf  = ws + OFF_WRF;
  unsigned short* wlb = (unsigned short*)(ws + OFF_WLF);  // bf16 wl for MFMA K4
  float* x1   = (float*)d_out;

  prep_kernel<<<1, 256, 0, stream>>>(g1, b1, m1, v1, g2, b2, m2, v2, g3, b3, m3, v3,
                                     gr, br, mr, vr, gl, bl, ml, vl, ge, be, me, ve,
                                     cw, misc);
  fold_kernel<<<(65536 + 255) / 256, 256, 0, stream>>>(w1, misc + MS_S1, w1f, 65536, 512);
  fold_kernel<<<(147456 + 255) / 256, 256, 0, stream>>>(w2, misc + MS_S2, w2f, 147456, 1152);
  fold_kernel<<<(65536 + 255) / 256, 256, 0, stream>>>(w3, misc + MS_S3, w3f, 65536, 128);
  fold_kernel<<<(262144 + 255) / 256, 256, 0, stream>>>(wr, misc + MS_SR, wrf, 262144, 512);
  fold_bf16_kernel<<<1024, 256, 0, stream>>>(wl, misc + MS_SL, wlb, 262144, 512);

  // K1: h1 = relu(conv1x1(x, w1f) + t1)
  gemm1x1_kernel<false, true><<<dim3(32, 1, 16), 256, 0, stream>>>(
      x, w1f, misc + MS_T1, nullptr, nullptr, nullptr, h1, 512, 0, 128);
  // K2: h2 = relu(conv3x3(h1, w2f) + t2)
  conv3x3_kernel<<<dim3(32, 1, 16), 256, 0, stream>>>(h1, w2f, misc + MS_T2, h2);
  // K3: x1 = relu(conv1x1(h2, w3f) + t3) + conv1x1(x, wrf) + tr
  gemm1x1_kernel<true, false><<<dim3(32, 4, 16), 256, 0, stream>>>(
      h2, w3f, misc + MS_T3, x, wrf, misc + MS_TR, x1, 128, 512, 512);
  // K4 (DIAGNOSTIC MFMA): y = relu(conv1x1(x1, wlb) + tl)
  mfma_lvc_kernel<<<dim3(32, 4, 16), 256, 0, stream>>>(wlb, x1, misc + MS_TL, y);
  // K5..: verified fp32 path
  assign_kernel<<<dim3(64, 16), 256, 0, stream>>>(y, cw, scale, misc, A);
  asum_kernel<<<1024, 256, 0, stream>>>(A, asum);
  enc_kernel<<<dim3(4, 8, 16), 256, 0, stream>>>(A, y, pe);
  engate_kernel<<<16, 256, 0, stream>>>(pe, asum, cw, misc, wfc, bfc, gam);
  final_kernel<<<32768, 256, 0, stream>>>((float*)d_out, gam);
}